// Round 10
// baseline (187.884 us; speedup 1.0000x reference)
//
#include <hip/hip_runtime.h>

typedef __bf16 bf16;
typedef __bf16 bf16x8 __attribute__((ext_vector_type(8)));
typedef __bf16 bf16x4 __attribute__((ext_vector_type(4)));
typedef float floatx4 __attribute__((ext_vector_type(4)));

#define HIDDEN 1024
#define SEQ 2048
#define BATCH 4
#define ATT_SCALE 0.0625f
#define LN_EPS 1e-5f
#define WW (HIDDEN * HIDDEN)

__device__ __forceinline__ void gload_lds16(const void* g, void* l) {
    __builtin_amdgcn_global_load_lds(
        (const __attribute__((address_space(1))) unsigned int*)g,
        (__attribute__((address_space(3))) unsigned int*)l, 16, 0, 0);
}

#define GBAR() asm volatile("s_barrier" ::: "memory")
#define MFMA(a, b, c) __builtin_amdgcn_mfma_f32_16x16x32_bf16(a, b, c, 0, 0, 0)

// ---------------- fp32 -> bf16 conversion ----------------
__global__ void cvt_f32_bf16(const float* __restrict__ in, bf16* __restrict__ out, int n4) {
    int i = blockIdx.x * blockDim.x + threadIdx.x;
    if (i >= n4) return;
    float4 v = ((const float4*)in)[i];
    bf16x4 o;
    o[0] = (bf16)v.x; o[1] = (bf16)v.y; o[2] = (bf16)v.z; o[3] = (bf16)v.w;
    ((bf16x4*)out)[i] = o;
}

// ---------------- transpose 3 weight matrices (fp32 1024x1024 -> bf16 transposed) ----------------
__global__ void transpose_w3(const float* __restrict__ s0, const float* __restrict__ s1,
                             const float* __restrict__ s2,
                             bf16* __restrict__ d0p, bf16* __restrict__ d1p, bf16* __restrict__ d2p) {
    const float* in = (blockIdx.z == 0) ? s0 : (blockIdx.z == 1) ? s1 : s2;
    bf16* out = (blockIdx.z == 0) ? d0p : (blockIdx.z == 1) ? d1p : d2p;
    __shared__ __attribute__((aligned(16))) bf16 tile[64][72];
    const int d0 = blockIdx.x * 64;
    const int f0 = blockIdx.y * 64;
    const int t = threadIdx.x;
    const int r = t >> 4;
    const int c = (t & 15) * 4;
#pragma unroll
    for (int i = 0; i < 4; ++i) {
        float4 v = *(const float4*)&in[(long)(f0 + r + i * 16) * HIDDEN + d0 + c];
        bf16x4 b;
        b[0] = (bf16)v.x; b[1] = (bf16)v.y; b[2] = (bf16)v.z; b[3] = (bf16)v.w;
        *(bf16x4*)&tile[r + i * 16][c] = b;
    }
    __syncthreads();
#pragma unroll
    for (int i = 0; i < 4; ++i) {
        const int dr = r + i * 16;
        bf16x4 o;
#pragma unroll
        for (int j = 0; j < 4; ++j) o[j] = tile[c + j][dr];
        *(bf16x4*)&out[(long)(d0 + dr) * HIDDEN + f0 + c] = o;
    }
}

// ---------------- GEMM: C = A (MxK_sub) * B^T, bf16 inputs, z = ks*zmod + mat ----------------
// 512 threads = 8 waves. BM=256. BNv=256: 2Mx4N waves, wave tile 128x64;
// BNv=128: 4Mx2N waves, wave tile 64x64. BK=64 (128B rows). 2-slot LDS dbuf.
// One barrier + one vmcnt(0) per K-tile; all fragment ds_reads issued up front,
// burst-stage of tile t+1 behind them; compiler's counted lgkm waits overlap
// later reads with earlier MFMA clusters. Rows stored with 16B-chunk rotation
// chunk'=(chunk+row)&7 -> measured-zero-conflict ds_read_b128; gload_lds dest
// linear, source carries inverse rotation (both-sides rule).
// z decomposition: mat = z % zmod (batch/matrix), ks = z / zmod (K-split).
// A += mat*sA + ks*K (column offset), B += mat*sB + ks*K; C plane = z*sC.
// MODE 0: bf16 C = acc*scale ; MODE 4: fp32 C = acc (split-K partial)
template <int BNv, int MODE>
__global__ __launch_bounds__(512, 2)
void gemm256(const bf16* A, const bf16* Bw, void* __restrict__ Cout,
             int lda, int ldb, int ldc, int K, float scale,
             long sA, long sB, long sC, int zmod) {
    constexpr int ABY = 256 * 128;          // 32 KB A-tile
    constexpr int BBY = BNv * 128;          // 32/16 KB B-tile
    constexpr int SLOT = ABY + BBY;
    constexpr int AU = ABY / 8192;
    constexpr int BU = BBY / 8192;
    constexpr int WNc = (BNv == 256) ? 4 : 2;
    constexpr int MR = (BNv == 256) ? 8 : 4;
    constexpr int MH = MR / 2;

    __shared__ __attribute__((aligned(16))) char lds[2 * SLOT];

    // XCD-aware block swizzle (all grids have nb % 8 == 0)
    const int gx = gridDim.x;
    const int nblk = gx * gridDim.y;
    const int bid = blockIdx.y * gx + blockIdx.x;
    const int cpx = nblk >> 3;
    const int sbid = (nblk & 7) ? bid : (bid & 7) * cpx + (bid >> 3);
    const int bx = sbid % gx, by = sbid / gx;

    const int z = blockIdx.z;
    const int mat = z % zmod, ks = z / zmod;
    const char* Ab = (const char*)(A + (long)mat * sA + (long)ks * K);
    const char* Bb = (const char*)(Bw + (long)mat * sB + (long)ks * K);
    const long lda2 = lda * 2L, ldb2 = ldb * 2L;

    const int t = threadIdx.x;
    const int lane = t & 63;
    const int w = t >> 6;
    const int wm = w / WNc, wn = w % WNc;
    const int l15 = lane & 15;
    const int l4 = lane >> 4;

    const int row0 = by * 256;
    const int col0 = bx * BNv;

    // staging source bases (inverse chunk rotation; unit offsets are uniform)
    const int srow = t >> 3;
    const int soff = (((t & 7) - (srow & 7)) & 7) * 16;
    const char* aP = Ab + (long)(row0 + srow) * lda2 + soff;
    const char* bP = Bb + (long)(col0 + srow) * ldb2 + soff;
    const int ld16 = t * 16;

    auto STAGE = [&](int slot, long koff) {
        char* base = &lds[slot * SLOT];
#pragma unroll
        for (int u = 0; u < AU; ++u)
            gload_lds16(aP + u * 64 * lda2 + koff, base + u * 8192 + ld16);
#pragma unroll
        for (int u = 0; u < BU; ++u)
            gload_lds16(bP + u * 64 * ldb2 + koff, base + ABY + u * 8192 + ld16);
    };

    floatx4 acc[MR][4] = {};
    const int nk = K / 64;

    STAGE(0, 0);
    asm volatile("s_waitcnt vmcnt(0)" ::: "memory");
    GBAR();

    for (int tt = 0; tt < nk; ++tt) {
        const char* sb = &lds[(tt & 1) * SLOT];

        auto RDA = [&](int m, int kkh) {
            int lr = wm * (MR * 16) + m * 16 + l15;
            return *(const bf16x8*)(sb + lr * 128 + (((kkh * 4 + l4 + lr) & 7) << 4));
        };
        auto RDB = [&](int n, int kkh) {
            int lr = wn * 64 + n * 16 + l15;
            return *(const bf16x8*)(sb + ABY + lr * 128 + (((kkh * 4 + l4 + lr) & 7) << 4));
        };

        bf16x8 alo[MH][2], ahi[MH][2], b0[2][2], b1[2][2];
#pragma unroll
        for (int m = 0; m < MH; ++m) { alo[m][0] = RDA(m, 0); alo[m][1] = RDA(m, 1); }
#pragma unroll
        for (int n = 0; n < 2; ++n) {
            b0[n][0] = RDB(n, 0); b0[n][1] = RDB(n, 1);
            b1[n][0] = RDB(2 + n, 0); b1[n][1] = RDB(2 + n, 1);
        }

        if (tt + 1 < nk) STAGE((tt + 1) & 1, (long)(tt + 1) * 128);

        __builtin_amdgcn_s_setprio(1);
#pragma unroll
        for (int m = 0; m < MH; ++m)
#pragma unroll
            for (int n = 0; n < 2; ++n) {
                acc[m][n] = MFMA(alo[m][0], b0[n][0], acc[m][n]);
                acc[m][n] = MFMA(alo[m][1], b0[n][1], acc[m][n]);
            }
        __builtin_amdgcn_s_setprio(0);

#pragma unroll
        for (int m = 0; m < MH; ++m) { ahi[m][0] = RDA(MH + m, 0); ahi[m][1] = RDA(MH + m, 1); }

        __builtin_amdgcn_s_setprio(1);
#pragma unroll
        for (int m = 0; m < MH; ++m)
#pragma unroll
            for (int n = 0; n < 2; ++n) {
                acc[m][2 + n] = MFMA(alo[m][0], b1[n][0], acc[m][2 + n]);
                acc[m][2 + n] = MFMA(alo[m][1], b1[n][1], acc[m][2 + n]);
            }
#pragma unroll
        for (int m = 0; m < MH; ++m)
#pragma unroll
            for (int n = 0; n < 2; ++n) {
                acc[MH + m][n] = MFMA(ahi[m][0], b0[n][0], acc[MH + m][n]);
                acc[MH + m][n] = MFMA(ahi[m][1], b0[n][1], acc[MH + m][n]);
            }
#pragma unroll
        for (int m = 0; m < MH; ++m)
#pragma unroll
            for (int n = 0; n < 2; ++n) {
                acc[MH + m][2 + n] = MFMA(ahi[m][0], b1[n][0], acc[MH + m][2 + n]);
                acc[MH + m][2 + n] = MFMA(ahi[m][1], b1[n][1], acc[MH + m][2 + n]);
            }
        __builtin_amdgcn_s_setprio(0);

        asm volatile("s_waitcnt vmcnt(0)" ::: "memory");
        GBAR();
    }

    // ---- epilogue
    const int rq = l4 * 4;
    if constexpr (MODE == 0) {
        bf16* C = ((bf16*)Cout) + (long)z * sC;
#pragma unroll
        for (int m = 0; m < MR; ++m)
#pragma unroll
            for (int i = 0; i < 4; ++i) {
                long gr = row0 + wm * (MR * 16) + m * 16 + rq + i;
#pragma unroll
                for (int n = 0; n < 4; ++n) {
                    int gc = col0 + wn * 64 + n * 16 + l15;
                    C[gr * ldc + gc] = (bf16)(acc[m][n][i] * scale);
                }
            }
    } else {
        float* C = (float*)Cout + (long)z * sC;
#pragma unroll
        for (int m = 0; m < MR; ++m)
#pragma unroll
            for (int i = 0; i < 4; ++i) {
                long gr = row0 + wm * (MR * 16) + m * 16 + rq + i;
#pragma unroll
                for (int n = 0; n < 4; ++n) {
                    int gc = col0 + wn * 64 + n * 16 + l15;
                    C[gr * ldc + gc] = acc[m][n][i];
                }
            }
    }
}

// ---------------- reduce Gt/Wc fp32 partials (planes z=ks*2+mat, ks 0..3) -> wgc bf16 ----------------
__global__ void reduce_wgc(const float* __restrict__ p, bf16* __restrict__ out) {
    int i = blockIdx.x * blockDim.x + threadIdx.x;   // float4 group over 2*WW
    int e = i * 4;
    int mat = e >> 20;                                // WW = 1<<20
    int local = e & (WW - 1);
    float4 s = *(const float4*)(p + (long)mat * WW + local);
#pragma unroll
    for (int ksp = 1; ksp < 4; ++ksp) {
        float4 a = *(const float4*)(p + (long)(ksp * 2 + mat) * WW + local);
        s.x += a.x; s.y += a.y; s.z += a.z; s.w += a.w;
    }
    bf16x4 o;
    o[0] = (bf16)s.x; o[1] = (bf16)s.y; o[2] = (bf16)s.z; o[3] = (bf16)s.w;
    *(bf16x4*)&out[e] = o;
}

// ---------------- row softmax, in-place on bf16 scores ----------------
__global__ void softmax_rows(bf16* __restrict__ S, const int* __restrict__ mask) {
    const int b = blockIdx.y;
    const int row = blockIdx.x;
    bf16* srow = S + ((long)b * SEQ + row) * SEQ;
    const int* mrow = mask + b * SEQ;
    const int t = threadIdx.x;

    bf16x8 sv = *(const bf16x8*)&srow[t * 8];
    int4 m0 = ((const int4*)mrow)[t * 2];
    int4 m1 = ((const int4*)mrow)[t * 2 + 1];
    int mk[8] = {m0.x, m0.y, m0.z, m0.w, m1.x, m1.y, m1.z, m1.w};

    float v[8];
    float mx = -1e30f;
#pragma unroll
    for (int j = 0; j < 8; ++j) {
        float s = (float)sv[j];
        if (mk[j] == 0) s = -1e9f;
        v[j] = s;
        mx = fmaxf(mx, s);
    }
    __shared__ float redm[4], reds[4];
#pragma unroll
    for (int off = 32; off > 0; off >>= 1) mx = fmaxf(mx, __shfl_down(mx, off));
    if ((t & 63) == 0) redm[t >> 6] = mx;
    __syncthreads();
    mx = fmaxf(fmaxf(redm[0], redm[1]), fmaxf(redm[2], redm[3]));

    float sum = 0.f;
#pragma unroll
    for (int j = 0; j < 8; ++j) {
        v[j] = __expf(v[j] - mx);
        sum += v[j];
    }
#pragma unroll
    for (int off = 32; off > 0; off >>= 1) sum += __shfl_down(sum, off);
    if ((t & 63) == 0) reds[t >> 6] = sum;
    __syncthreads();
    sum = reds[0] + reds[1] + reds[2] + reds[3];
    float inv = 1.0f / sum;

    bf16x8 o;
#pragma unroll
    for (int j = 0; j < 8; ++j) o[j] = (bf16)(v[j] * inv);
    *(bf16x8*)&srow[t * 8] = o;
}

// ---------------- transpose VWc (from yv cols 1024..2047): per batch -> (1024 x SEQ) ----------------
__global__ void transpose_v(const bf16* __restrict__ yv, bf16* __restrict__ out) {
    __shared__ __attribute__((aligned(16))) bf16 tile[64][72];
    const int z = blockIdx.z;
    const bf16* ib = yv + (long)z * SEQ * 2048 + 1024;
    bf16* ob = out + (long)z * SEQ * HIDDEN;
    const int d0 = blockIdx.x * 64;
    const int s0 = blockIdx.y * 64;
    const int t = threadIdx.x;
    const int r = t >> 4;
    const int c = (t & 15) * 4;
#pragma unroll
    for (int i = 0; i < 4; ++i) {
        bf16x4 v = *(const bf16x4*)&ib[(long)(s0 + r + i * 16) * 2048 + d0 + c];
        *(bf16x4*)&tile[r + i * 16][c] = v;
    }
    __syncthreads();
#pragma unroll
    for (int i = 0; i < 4; ++i) {
        const int dr = r + i * 16;
        bf16x4 o;
#pragma unroll
        for (int j = 0; j < 4; ++j) o[j] = tile[c + j][dr];
        *(bf16x4*)&ob[(long)(d0 + dr) * SEQ + s0 + c] = o;
    }
}

// ---------------- LayerNorm fused with PV split-K reduce + bias + residual ----------------
// h = p0 + p1 + bo + x ; out = LN(h)*gamma + beta.  pp planes: z = ks*4 + b.
__global__ void layernorm_out(const bf16* __restrict__ pp, const float* __restrict__ x,
                              const float* __restrict__ bo, const float* __restrict__ gamma,
                              const float* __restrict__ beta, float* __restrict__ out) {
    const long row = blockIdx.x;
    const int b = (int)(row >> 11);
    const int s = (int)(row & 2047);
    const bf16* r0 = pp + ((long)b * SEQ + s) * HIDDEN;
    const bf16* r1 = r0 + 4L * SEQ * HIDDEN;
    const int t = threadIdx.x;

    bf16x4 a0 = ((const bf16x4*)r0)[t];
    bf16x4 a1 = ((const bf16x4*)r1)[t];
    float4 xv = ((const float4*)(x + row * HIDDEN))[t];
    float4 bv = ((const float4*)bo)[t];
    float4 v;
    v.x = (float)a0[0] + (float)a1[0] + bv.x + xv.x;
    v.y = (float)a0[1] + (float)a1[1] + bv.y + xv.y;
    v.z = (float)a0[2] + (float)a1[2] + bv.z + xv.z;
    v.w = (float)a0[3] + (float)a1[3] + bv.w + xv.w;

    float ssum = v.x + v.y + v.z + v.w;
    float sq = v.x * v.x + v.y * v.y + v.z * v.z + v.w * v.w;
    __shared__ float rs[4], rq[4];
#pragma unroll
    for (int off = 32; off > 0; off >>= 1) {
        ssum += __shfl_down(ssum, off);
        sq += __shfl_down(sq, off);
    }
    if ((t & 63) == 0) { rs[t >> 6] = ssum; rq[t >> 6] = sq; }
    __syncthreads();
    ssum = rs[0] + rs[1] + rs[2] + rs[3];
    sq = rq[0] + rq[1] + rq[2] + rq[3];
    float mu = ssum * (1.0f / HIDDEN);
    float var = sq * (1.0f / HIDDEN) - mu * mu;
    float rinv = rsqrtf(var + LN_EPS);
    float4 g = ((const float4*)gamma)[t];
    float4 bt = ((const float4*)beta)[t];
    float4 o;
    o.x = (v.x - mu) * rinv * g.x + bt.x;
    o.y = (v.y - mu) * rinv * g.y + bt.y;
    o.z = (v.z - mu) * rinv * g.z + bt.z;
    o.w = (v.w - mu) * rinv * g.w + bt.w;
    ((float4*)(out + row * HIDDEN))[t] = o;
}

// ---------------- launch ----------------
extern "C" void kernel_launch(void* const* d_in, const int* in_sizes, int n_in,
                              void* d_out, int out_size, void* d_ws, size_t ws_size,
                              hipStream_t stream) {
    const float* x     = (const float*)d_in[0];
    const int*   mask  = (const int*)d_in[1];
    const float* Wq    = (const float*)d_in[2];
    const float* Wk    = (const float*)d_in[3];
    const float* Wv    = (const float*)d_in[4];
    const float* Wo    = (const float*)d_in[5];
    const float* bo    = (const float*)d_in[6];
    const float* gamma = (const float*)d_in[7];
    const float* beta  = (const float*)d_in[8];
    float* out = (float*)d_out;

    char* ws = (char*)d_ws;
    const long MB = 1024L * 1024L;
    bf16* yv   = (bf16*)(ws + 0 * MB);    // 32 MB (8192 x 2048) [y | VWc]
    bf16* pp   = (bf16*)(ws + 0 * MB);    // 32 MB PV partials (8 planes), after yv dead
    bf16* xb   = (bf16*)(ws + 32 * MB);   // 16 MB
    bf16* vt   = (bf16*)(ws + 48 * MB);   // 16 MB (per batch 1024 x 2048)
    bf16* wgc  = (bf16*)(ws + 64 * MB);   // 4 MB (2048 x 1024): [Gt ; Wc]
    bf16* wkT  = (bf16*)(ws + 68 * MB);   // 2 MB  -- A mat 0
    bf16* wo   = (bf16*)(ws + 70 * MB);   // 2 MB  -- A mat 1
    bf16* wqT  = (bf16*)(ws + 72 * MB);   // 2 MB  -- B mat 0
    bf16* wvT  = (bf16*)(ws + 74 * MB);   // 2 MB  -- B mat 1
    bf16* S    = (bf16*)(ws + 76 * MB);   // 32 MB scores/probs
    float* wgcp = (float*)(ws + 76 * MB); // 32 MB fp32 Gt/Wc partials (before S exists)

    const int BS = BATCH * SEQ;  // 8192
    dim3 blk256(256), blk512(512);

    // input + weight prep
    cvt_f32_bf16<<<dim3(BS * HIDDEN / 4 / 256), blk256, 0, stream>>>(x, xb, BS * HIDDEN / 4);
    cvt_f32_bf16<<<dim3(WW / 4 / 256), blk256, 0, stream>>>(Wo, wo, WW / 4);
    transpose_w3<<<dim3(16, 16, 3), blk256, 0, stream>>>(Wq, Wk, Wv, wqT, wkT, wvT);

    // Gt/Wc split-K=4: z = ks*2 + mat, K_sub=256, fp32 partials. grid (8,4,8) = 256 WGs
    gemm256<128, 4><<<dim3(HIDDEN / 128, HIDDEN / 256, 8), blk512, 0, stream>>>(
        wkT, wqT, wgcp, HIDDEN, HIDDEN, HIDDEN, 256, 1.0f,
        (long)WW, (long)WW, (long)WW, 2);
    reduce_wgc<<<dim3(2 * WW / 4 / 256), blk256, 0, stream>>>(wgcp, wgc);

    // fused projection: yv = xb * wgc^T  (8192 x 2048)  grid 8x32 = 256
    gemm256<256, 0><<<dim3(2048 / 256, BS / 256, 1), blk512, 0, stream>>>(
        xb, wgc, yv, HIDDEN, HIDDEN, 2048, HIDDEN, 1.0f, 0, 0, 0, 1);

    // VWc -> vt per batch
    transpose_v<<<dim3(HIDDEN / 64, SEQ / 64, BATCH), blk256, 0, stream>>>(yv, vt);

    // scores: per batch (2048x2048) = y * x^T * SCALE  grid 8x8x4 = 256
    gemm256<256, 0><<<dim3(SEQ / 256, SEQ / 256, BATCH), blk512, 0, stream>>>(
        yv, xb, S, 2048, HIDDEN, SEQ, HIDDEN, ATT_SCALE,
        (long)SEQ * 2048, (long)SEQ * HIDDEN, (long)SEQ * SEQ, 4);

    softmax_rows<<<dim3(SEQ, BATCH), blk256, 0, stream>>>(S, mask);

    // PV split-K=2: z = ks*4 + b, K_sub=1024, bf16 partials -> pp. grid (8,8,8) = 512 WGs
    gemm256<128, 0><<<dim3(HIDDEN / 128, SEQ / 256, 8), blk512, 0, stream>>>(
        S, vt, pp, SEQ, SEQ, HIDDEN, 1024, 1.0f,
        (long)SEQ * SEQ, (long)HIDDEN * SEQ, (long)SEQ * HIDDEN, 4);

    // LN fused with partial-reduce + bias + residual
    layernorm_out<<<dim3(BS), blk256, 0, stream>>>(pp, x, bo, gamma, beta, out);
}

// Round 11
// 186.810 us; speedup vs baseline: 1.0058x; 1.0058x over previous
//
#include <hip/hip_runtime.h>

typedef __bf16 bf16;
typedef __bf16 bf16x8 __attribute__((ext_vector_type(8)));
typedef __bf16 bf16x4 __attribute__((ext_vector_type(4)));
typedef float floatx4 __attribute__((ext_vector_type(4)));

#define HIDDEN 1024
#define SEQ 2048
#define BATCH 4
#define ATT_SCALE 0.0625f
#define LN_EPS 1e-5f
#define WW (HIDDEN * HIDDEN)

__device__ __forceinline__ void gload_lds16(const void* g, void* l) {
    __builtin_amdgcn_global_load_lds(
        (const __attribute__((address_space(1))) unsigned int*)g,
        (__attribute__((address_space(3))) unsigned int*)l, 16, 0, 0);
}

#define GBAR() asm volatile("s_barrier" ::: "memory")
#define LGKM0() do { asm volatile("s_waitcnt lgkmcnt(0)" ::: "memory"); \
                     __builtin_amdgcn_sched_barrier(0); } while (0)
#define VMC(N) asm volatile("s_waitcnt vmcnt(" #N ")" ::: "memory")
#define MFMA(a, b, c) __builtin_amdgcn_mfma_f32_16x16x32_bf16(a, b, c, 0, 0, 0)

// ---------------- fp32 -> bf16 conversion ----------------
__global__ void cvt_f32_bf16(const float* __restrict__ in, bf16* __restrict__ out, int n4) {
    int i = blockIdx.x * blockDim.x + threadIdx.x;
    if (i >= n4) return;
    float4 v = ((const float4*)in)[i];
    bf16x4 o;
    o[0] = (bf16)v.x; o[1] = (bf16)v.y; o[2] = (bf16)v.z; o[3] = (bf16)v.w;
    ((bf16x4*)out)[i] = o;
}

// ---------------- transpose 3 weight matrices (fp32 1024x1024 -> bf16 transposed) ----------------
__global__ void transpose_w3(const float* __restrict__ s0, const float* __restrict__ s1,
                             const float* __restrict__ s2,
                             bf16* __restrict__ d0p, bf16* __restrict__ d1p, bf16* __restrict__ d2p) {
    const float* in = (blockIdx.z == 0) ? s0 : (blockIdx.z == 1) ? s1 : s2;
    bf16* out = (blockIdx.z == 0) ? d0p : (blockIdx.z == 1) ? d1p : d2p;
    __shared__ __attribute__((aligned(16))) bf16 tile[64][72];
    const int d0 = blockIdx.x * 64;
    const int f0 = blockIdx.y * 64;
    const int t = threadIdx.x;
    const int r = t >> 4;
    const int c = (t & 15) * 4;
#pragma unroll
    for (int i = 0; i < 4; ++i) {
        float4 v = *(const float4*)&in[(long)(f0 + r + i * 16) * HIDDEN + d0 + c];
        bf16x4 b;
        b[0] = (bf16)v.x; b[1] = (bf16)v.y; b[2] = (bf16)v.z; b[3] = (bf16)v.w;
        *(bf16x4*)&tile[r + i * 16][c] = b;
    }
    __syncthreads();
#pragma unroll
    for (int i = 0; i < 4; ++i) {
        const int dr = r + i * 16;
        bf16x4 o;
#pragma unroll
        for (int j = 0; j < 4; ++j) o[j] = tile[c + j][dr];
        *(bf16x4*)&out[(long)(d0 + dr) * HIDDEN + f0 + c] = o;
    }
}

// ---------------- 8-phase GEMM: C = A (MxK_sub) * B^T, bf16, z = ks*zmod + mat -------
// 512 thr = 8 waves (2M x 4N), BM=BN=256, wave tile 128x64, BK=64.
// LDS 128KB: 2 bufs x 4 units {A-k0, B-k0, A-k1, B-k1}, each 16KB = 256 rows x 64B,
// 16B-chunk rotation (row>>1)&3 (measured-zero-conflict ds_read_b128); gload_lds
// dest linear, source inverse-rotated. 4 phases per K-tile, 16 MFMA each; ONE
// 2-gload unit staged per phase; counted vmcnt(4) only at ends of ph1/ph3 (the
// 2 units it completes were staged 3-4 phases earlier -> wait ~free; loads span
// barriers, never drained). MODE 0: bf16 C=acc*scale ; MODE 4: fp32 C=acc.
template <int MODE>
__global__ __launch_bounds__(512, 2)
void gemm8p(const bf16* A, const bf16* Bw, void* __restrict__ Cout,
            int lda, int ldb, int ldc, int K, float scale,
            long sA, long sB, long sC, int zmod) {
    __shared__ __attribute__((aligned(16))) char lds[131072];

    // XCD-aware block swizzle (per-z nblk % 8 == 0 for all launches)
    const int gx = gridDim.x;
    const int nblk = gx * gridDim.y;
    const int bid = blockIdx.y * gx + blockIdx.x;
    const int cpx = nblk >> 3;
    const int sbid = (nblk & 7) ? bid : (bid & 7) * cpx + (bid >> 3);
    const int bx = sbid % gx, by = sbid / gx;

    const int z = blockIdx.z;
    const int mat = z % zmod, ks = z / zmod;
    const char* Ab = (const char*)(A + (long)mat * sA + (long)ks * K);
    const char* Bb = (const char*)(Bw + (long)mat * sB + (long)ks * K);
    const long lda2 = lda * 2L, ldb2 = ldb * 2L;

    const int t = threadIdx.x;
    const int lane = t & 63;
    const int w = t >> 6;
    const int wm = w >> 2;      // 0..1
    const int wn = w & 3;       // 0..3
    const int l15 = lane & 15;
    const int l4 = lane >> 4;

    const int row0 = by * 256;
    const int col0 = bx * 256;

    // staging sources: unit covers 256 rows x 64B; thread t, sub uu: row = uu*128 + t/4,
    // stored chunk (t&3) holds global chunk ((t&3) - ((row>>1)&3)) & 3
    const int sc = ((((t & 3) - ((t >> 3) & 3)) & 3) << 4);
    const char* aS[2];
    const char* bS[2];
#pragma unroll
    for (int uu = 0; uu < 2; ++uu) {
        aS[uu] = Ab + (long)(row0 + uu * 128 + (t >> 2)) * lda2 + sc;
        bS[uu] = Bb + (long)(col0 + uu * 128 + (t >> 2)) * ldb2 + sc;
    }

    auto STAGE = [&](char* dstu, const char* const* sp, long koff) {
        gload_lds16(sp[0] + koff, dstu + t * 16);
        gload_lds16(sp[1] + koff, dstu + 8192 + t * 16);
    };

    floatx4 acc[8][4] = {};
    const int nk = K / 64;

    // prologue: tile0's 4 units in consumption-wait order
    STAGE(lds + 0,     aS, 0);      // A-k0
    STAGE(lds + 16384, bS, 0);      // B-k0
    STAGE(lds + 32768, aS, 64);     // A-k1
    STAGE(lds + 49152, bS, 64);     // B-k1
    VMC(4);                          // A-k0, B-k0 landed
    GBAR();

    for (int tt = 0; tt < nk; ++tt) {
        const char* cb = lds + (tt & 1) * 65536;
        char* nb = lds + ((tt & 1) ^ 1) * 65536;
        const long nko = (long)((tt + 1 < nk) ? tt + 1 : nk - 1) * 128;

        auto RDA = [&](int kk, int m) {
            int lr = wm * 128 + m * 16 + l15;
            return *(const bf16x8*)(cb + kk * 32768 + lr * 64 + ((((lr >> 1) + l4) & 3) << 4));
        };
        auto RDB = [&](int kk, int n) {
            int lr = wn * 64 + n * 16 + l15;
            return *(const bf16x8*)(cb + 16384 + kk * 32768 + lr * 64 + ((((lr >> 1) + l4) & 3) << 4));
        };

        bf16x8 a[4], b0[4], b1[4];

        // ---- phase 0: A-k0 m0-3 + B-k0; stage A-k0(t+1)
#pragma unroll
        for (int m = 0; m < 4; ++m) a[m] = RDA(0, m);
#pragma unroll
        for (int n = 0; n < 4; ++n) b0[n] = RDB(0, n);
        STAGE(nb + 0, aS, nko);
        GBAR();
        LGKM0();
        __builtin_amdgcn_s_setprio(1);
#pragma unroll
        for (int m = 0; m < 4; ++m)
#pragma unroll
            for (int n = 0; n < 4; ++n) acc[m][n] = MFMA(a[m], b0[n], acc[m][n]);
        __builtin_amdgcn_s_setprio(0);
        GBAR();

        // ---- phase 1: A-k0 m4-7; stage B-k0(t+1); W: A-k1,B-k1(t) landed
#pragma unroll
        for (int m = 0; m < 4; ++m) a[m] = RDA(0, 4 + m);
        STAGE(nb + 16384, bS, nko);
        GBAR();
        LGKM0();
        __builtin_amdgcn_s_setprio(1);
#pragma unroll
        for (int m = 0; m < 4; ++m)
#pragma unroll
            for (int n = 0; n < 4; ++n) acc[4 + m][n] = MFMA(a[m], b0[n], acc[4 + m][n]);
        __builtin_amdgcn_s_setprio(0);
        VMC(4);
        GBAR();

        // ---- phase 2: A-k1 m0-3 + B-k1; stage A-k1(t+1)
#pragma unroll
        for (int m = 0; m < 4; ++m) a[m] = RDA(1, m);
#pragma unroll
        for (int n = 0; n < 4; ++n) b1[n] = RDB(1, n);
        STAGE(nb + 32768, aS, nko + 64);
        GBAR();
        LGKM0();
        __builtin_amdgcn_s_setprio(1);
#pragma unroll
        for (int m = 0; m < 4; ++m)
#pragma unroll
            for (int n = 0; n < 4; ++n) acc[m][n] = MFMA(a[m], b1[n], acc[m][n]);
        __builtin_amdgcn_s_setprio(0);
        GBAR();

        // ---- phase 3: A-k1 m4-7; stage B-k1(t+1); W: A-k0,B-k0(t+1) landed
#pragma unroll
        for (int m = 0; m < 4; ++m) a[m] = RDA(1, 4 + m);
        STAGE(nb + 49152, bS, nko + 64);
        GBAR();
        LGKM0();
        __builtin_amdgcn_s_setprio(1);
#pragma unroll
        for (int m = 0; m < 4; ++m)
#pragma unroll
            for (int n = 0; n < 4; ++n) acc[4 + m][n] = MFMA(a[m], b1[n], acc[4 + m][n]);
        __builtin_amdgcn_s_setprio(0);
        VMC(4);
        GBAR();
    }
    VMC(0);

    // ---- epilogue
    const int rq = l4 * 4;
    if constexpr (MODE == 0) {
        bf16* C = ((bf16*)Cout) + (long)z * sC;
#pragma unroll
        for (int m = 0; m < 8; ++m)
#pragma unroll
            for (int i = 0; i < 4; ++i) {
                long gr = row0 + wm * 128 + m * 16 + rq + i;
#pragma unroll
                for (int n = 0; n < 4; ++n) {
                    int gc = col0 + wn * 64 + n * 16 + l15;
                    C[gr * ldc + gc] = (bf16)(acc[m][n][i] * scale);
                }
            }
    } else {
        float* C = (float*)Cout + (long)z * sC;
#pragma unroll
        for (int m = 0; m < 8; ++m)
#pragma unroll
            for (int i = 0; i < 4; ++i) {
                long gr = row0 + wm * 128 + m * 16 + rq + i;
#pragma unroll
                for (int n = 0; n < 4; ++n) {
                    int gc = col0 + wn * 64 + n * 16 + l15;
                    C[gr * ldc + gc] = acc[m][n][i];
                }
            }
    }
}

// ---------------- reduce Gt/Wc fp32 partials (planes z=ks*2+mat, ks 0..3) -> wgc bf16 ----------------
__global__ void reduce_wgc(const float* __restrict__ p, bf16* __restrict__ out) {
    int i = blockIdx.x * blockDim.x + threadIdx.x;
    int e = i * 4;
    int mat = e >> 20;
    int local = e & (WW - 1);
    float4 s = *(const float4*)(p + (long)mat * WW + local);
#pragma unroll
    for (int ksp = 1; ksp < 4; ++ksp) {
        float4 a = *(const float4*)(p + (long)(ksp * 2 + mat) * WW + local);
        s.x += a.x; s.y += a.y; s.z += a.z; s.w += a.w;
    }
    bf16x4 o;
    o[0] = (bf16)s.x; o[1] = (bf16)s.y; o[2] = (bf16)s.z; o[3] = (bf16)s.w;
    *(bf16x4*)&out[e] = o;
}

// ---------------- row softmax, in-place on bf16 scores ----------------
__global__ void softmax_rows(bf16* __restrict__ S, const int* __restrict__ mask) {
    const int b = blockIdx.y;
    const int row = blockIdx.x;
    bf16* srow = S + ((long)b * SEQ + row) * SEQ;
    const int* mrow = mask + b * SEQ;
    const int t = threadIdx.x;

    bf16x8 sv = *(const bf16x8*)&srow[t * 8];
    int4 m0 = ((const int4*)mrow)[t * 2];
    int4 m1 = ((const int4*)mrow)[t * 2 + 1];
    int mk[8] = {m0.x, m0.y, m0.z, m0.w, m1.x, m1.y, m1.z, m1.w};

    float v[8];
    float mx = -1e30f;
#pragma unroll
    for (int j = 0; j < 8; ++j) {
        float s = (float)sv[j];
        if (mk[j] == 0) s = -1e9f;
        v[j] = s;
        mx = fmaxf(mx, s);
    }
    __shared__ float redm[4], reds[4];
#pragma unroll
    for (int off = 32; off > 0; off >>= 1) mx = fmaxf(mx, __shfl_down(mx, off));
    if ((t & 63) == 0) redm[t >> 6] = mx;
    __syncthreads();
    mx = fmaxf(fmaxf(redm[0], redm[1]), fmaxf(redm[2], redm[3]));

    float sum = 0.f;
#pragma unroll
    for (int j = 0; j < 8; ++j) {
        v[j] = __expf(v[j] - mx);
        sum += v[j];
    }
#pragma unroll
    for (int off = 32; off > 0; off >>= 1) sum += __shfl_down(sum, off);
    if ((t & 63) == 0) reds[t >> 6] = sum;
    __syncthreads();
    sum = reds[0] + reds[1] + reds[2] + reds[3];
    float inv = 1.0f / sum;

    bf16x8 o;
#pragma unroll
    for (int j = 0; j < 8; ++j) o[j] = (bf16)(v[j] * inv);
    *(bf16x8*)&srow[t * 8] = o;
}

// ---------------- transpose VWc (from yv cols 1024..2047): per batch -> (1024 x SEQ) ----------------
__global__ void transpose_v(const bf16* __restrict__ yv, bf16* __restrict__ out) {
    __shared__ __attribute__((aligned(16))) bf16 tile[64][72];
    const int z = blockIdx.z;
    const bf16* ib = yv + (long)z * SEQ * 2048 + 1024;
    bf16* ob = out + (long)z * SEQ * HIDDEN;
    const int d0 = blockIdx.x * 64;
    const int s0 = blockIdx.y * 64;
    const int t = threadIdx.x;
    const int r = t >> 4;
    const int c = (t & 15) * 4;
#pragma unroll
    for (int i = 0; i < 4; ++i) {
        bf16x4 v = *(const bf16x4*)&ib[(long)(s0 + r + i * 16) * 2048 + d0 + c];
        *(bf16x4*)&tile[r + i * 16][c] = v;
    }
    __syncthreads();
#pragma unroll
    for (int i = 0; i < 4; ++i) {
        const int dr = r + i * 16;
        bf16x4 o;
#pragma unroll
        for (int j = 0; j < 4; ++j) o[j] = tile[c + j][dr];
        *(bf16x4*)&ob[(long)(d0 + dr) * SEQ + s0 + c] = o;
    }
}

// ---------------- LayerNorm fused with PV split-K reduce + bias + residual ----------------
__global__ void layernorm_out(const bf16* __restrict__ pp, const float* __restrict__ x,
                              const float* __restrict__ bo, const float* __restrict__ gamma,
                              const float* __restrict__ beta, float* __restrict__ out) {
    const long row = blockIdx.x;
    const int b = (int)(row >> 11);
    const int s = (int)(row & 2047);
    const bf16* r0 = pp + ((long)b * SEQ + s) * HIDDEN;
    const bf16* r1 = r0 + 4L * SEQ * HIDDEN;
    const int t = threadIdx.x;

    bf16x4 a0 = ((const bf16x4*)r0)[t];
    bf16x4 a1 = ((const bf16x4*)r1)[t];
    float4 xv = ((const float4*)(x + row * HIDDEN))[t];
    float4 bv = ((const float4*)bo)[t];
    float4 v;
    v.x = (float)a0[0] + (float)a1[0] + bv.x + xv.x;
    v.y = (float)a0[1] + (float)a1[1] + bv.y + xv.y;
    v.z = (float)a0[2] + (float)a1[2] + bv.z + xv.z;
    v.w = (float)a0[3] + (float)a1[3] + bv.w + xv.w;

    float ssum = v.x + v.y + v.z + v.w;
    float sq = v.x * v.x + v.y * v.y + v.z * v.z + v.w * v.w;
    __shared__ float rs[4], rq[4];
#pragma unroll
    for (int off = 32; off > 0; off >>= 1) {
        ssum += __shfl_down(ssum, off);
        sq += __shfl_down(sq, off);
    }
    if ((t & 63) == 0) { rs[t >> 6] = ssum; rq[t >> 6] = sq; }
    __syncthreads();
    ssum = rs[0] + rs[1] + rs[2] + rs[3];
    sq = rq[0] + rq[1] + rq[2] + rq[3];
    float mu = ssum * (1.0f / HIDDEN);
    float var = sq * (1.0f / HIDDEN) - mu * mu;
    float rinv = rsqrtf(var + LN_EPS);
    float4 g = ((const float4*)gamma)[t];
    float4 bt = ((const float4*)beta)[t];
    float4 o;
    o.x = (v.x - mu) * rinv * g.x + bt.x;
    o.y = (v.y - mu) * rinv * g.y + bt.y;
    o.z = (v.z - mu) * rinv * g.z + bt.z;
    o.w = (v.w - mu) * rinv * g.w + bt.w;
    ((float4*)(out + row * HIDDEN))[t] = o;
}

// ---------------- launch ----------------
extern "C" void kernel_launch(void* const* d_in, const int* in_sizes, int n_in,
                              void* d_out, int out_size, void* d_ws, size_t ws_size,
                              hipStream_t stream) {
    const float* x     = (const float*)d_in[0];
    const int*   mask  = (const int*)d_in[1];
    const float* Wq    = (const float*)d_in[2];
    const float* Wk    = (const float*)d_in[3];
    const float* Wv    = (const float*)d_in[4];
    const float* Wo    = (const float*)d_in[5];
    const float* bo    = (const float*)d_in[6];
    const float* gamma = (const float*)d_in[7];
    const float* beta  = (const float*)d_in[8];
    float* out = (float*)d_out;

    char* ws = (char*)d_ws;
    const long MB = 1024L * 1024L;
    bf16* yv   = (bf16*)(ws + 0 * MB);    // 32 MB (8192 x 2048) [y | VWc]
    bf16* pp   = (bf16*)(ws + 0 * MB);    // 32 MB PV partials (8 planes), after yv dead
    bf16* xb   = (bf16*)(ws + 32 * MB);   // 16 MB
    bf16* vt   = (bf16*)(ws + 48 * MB);   // 16 MB (per batch 1024 x 2048)
    bf16* wgc  = (bf16*)(ws + 64 * MB);   // 4 MB (2048 x 1024): [Gt ; Wc]
    bf16* wkT  = (bf16*)(ws + 68 * MB);   // 2 MB  -- A mat 0
    bf16* wo   = (bf16*)(ws + 70 * MB);   // 2 MB  -- A mat 1
    bf16* wqT  = (bf16*)(ws + 72 * MB);   // 2 MB  -- B mat 0
    bf16* wvT  = (bf16*)(ws + 74 * MB);   // 2 MB  -- B mat 1
    bf16* S    = (bf16*)(ws + 76 * MB);   // 32 MB scores/probs
    float* wgcp = (float*)(ws + 76 * MB); // 32 MB fp32 Gt/Wc partials (before S exists)

    const int BS = BATCH * SEQ;  // 8192
    dim3 blk256(256), blk512(512);

    // input + weight prep
    cvt_f32_bf16<<<dim3(BS * HIDDEN / 4 / 256), blk256, 0, stream>>>(x, xb, BS * HIDDEN / 4);
    cvt_f32_bf16<<<dim3(WW / 4 / 256), blk256, 0, stream>>>(Wo, wo, WW / 4);
    transpose_w3<<<dim3(16, 16, 3), blk256, 0, stream>>>(Wq, Wk, Wv, wqT, wkT, wvT);

    // Gt/Wc split-K=4: z = ks*2 + mat, K_sub=256 (4 tiles), fp32 partials. grid (4,4,8)
    gemm8p<4><<<dim3(1024 / 256, 1024 / 256, 8), blk512, 0, stream>>>(
        wkT, wqT, wgcp, HIDDEN, HIDDEN, HIDDEN, 256, 1.0f,
        (long)WW, (long)WW, (long)WW, 2);
    reduce_wgc<<<dim3(2 * WW / 4 / 256), blk256, 0, stream>>>(wgcp, wgc);

    // fused projection: yv = xb * wgc^T (8192 x 2048), K=1024. grid 8x32 = 256
    gemm8p<0><<<dim3(2048 / 256, BS / 256, 1), blk512, 0, stream>>>(
        xb, wgc, yv, HIDDEN, HIDDEN, 2048, HIDDEN, 1.0f, 0, 0, 0, 1);

    // VWc -> vt per batch
    transpose_v<<<dim3(HIDDEN / 64, SEQ / 64, BATCH), blk256, 0, stream>>>(yv, vt);

    // scores: per batch (2048x2048) = y * x^T * SCALE. grid 8x8x4 = 256
    gemm8p<0><<<dim3(SEQ / 256, SEQ / 256, BATCH), blk512, 0, stream>>>(
        yv, xb, S, 2048, HIDDEN, SEQ, HIDDEN, ATT_SCALE,
        (long)SEQ * 2048, (long)SEQ * HIDDEN, (long)SEQ * SEQ, 4);

    softmax_rows<<<dim3(SEQ, BATCH), blk256, 0, stream>>>(S, mask);

    // PV split-K=2: z = ks*4 + b, K_sub=1024 (16 tiles), bf16 partials. grid (4,8,8) = 256
    gemm8p<0><<<dim3(HIDDEN / 256, SEQ / 256, 8), blk512, 0, stream>>>(
        S, vt, pp, SEQ, SEQ, HIDDEN, 1024, 1.0f,
        (long)SEQ * SEQ, (long)HIDDEN * SEQ, (long)SEQ * HIDDEN, 4);

    // LN fused with partial-reduce + bias + residual
    layernorm_out<<<dim3(BS), blk256, 0, stream>>>(pp, x, bo, gamma, beta, out);
}